// Round 3
// baseline (880.972 us; speedup 1.0000x reference)
//
#include <hip/hip_runtime.h>
#include <stdint.h>

#define NN 2048
#define FF 64
#define NB 32

typedef __attribute__((ext_vector_type(8))) short bf16x8;
typedef __attribute__((ext_vector_type(4))) float f32x4;

__device__ __forceinline__ uint16_t f2bf(float f) {
  uint32_t u = __builtin_bit_cast(uint32_t, f);
  return (uint16_t)((u + 0x7FFFu + ((u >> 16) & 1u)) >> 16);  // RNE truncation
}
__device__ __forceinline__ float bf2f(uint16_t h) {
  uint32_t u = ((uint32_t)h) << 16;
  return __builtin_bit_cast(float, u);
}

// ---------------- W [64(k)][64(f)] fp32 -> Wt [64(f)][64(k)] bf16 ----------------
__global__ void k_prep(const float* __restrict__ W, uint16_t* __restrict__ Wt) {
  int t = threadIdx.x;  // 256
  for (int i = 0; i < 16; ++i) {
    int idx = t * 16 + i;  // = k*64 + f
    int k = idx >> 6, f = idx & 63;
    Wt[f * 64 + k] = f2bf(W[idx]);
  }
}

// ------- xw = x @ W (bf16), writes BOTH [b][n][f] and transposed [b][f][n] -------
__global__ __launch_bounds__(256) void k_xw(const float* __restrict__ x,
                                            const uint16_t* __restrict__ Wt,
                                            uint16_t* __restrict__ xw,
                                            uint16_t* __restrict__ xwT) {
  __shared__ short As[64 * 72];  // x tile bf16 (stride 72); reused as transpose buf
  int bid = blockIdx.x;
  int b = bid >> 5;
  int n0 = (bid & 31) * 64;
  int t = threadIdx.x;
  const float* xb = x + ((size_t)b * NN + n0) * FF;
  for (int i = 0; i < 4; ++i) {
    int idx = t + i * 256;  // 1024 float4 chunks
    int r = idx >> 4, c = (idx & 15) * 4;
    float4 v = *(const float4*)(xb + r * FF + c);
    uint32_t p0 = f2bf(v.x) | ((uint32_t)f2bf(v.y) << 16);
    uint32_t p1 = f2bf(v.z) | ((uint32_t)f2bf(v.w) << 16);
    uint2 pv = {p0, p1};
    *(uint2*)&As[r * 72 + c] = pv;
  }
  __syncthreads();
  int lane = t & 63, wave = t >> 6;
  int l16 = lane & 15, quad = lane >> 4;
  f32x4 acc[4] = {};
  for (int ks = 0; ks < 2; ++ks) {
    bf16x8 a = *(const bf16x8*)&As[(wave * 16 + l16) * 72 + ks * 32 + quad * 8];
    for (int fi = 0; fi < 4; ++fi) {
      bf16x8 bq = *(const bf16x8*)(Wt + (fi * 16 + l16) * 64 + ks * 32 + quad * 8);
      acc[fi] = __builtin_amdgcn_mfma_f32_16x16x32_bf16(a, bq, acc[fi], 0, 0, 0);
    }
  }
  for (int fi = 0; fi < 4; ++fi)
    for (int r = 0; r < 4; ++r) {
      int n = n0 + wave * 16 + quad * 4 + r;
      int f = fi * 16 + l16;
      xw[((size_t)b * NN + n) * FF + f] = f2bf(acc[fi][r]);
    }
  // fused transpose: stage tile as [f][n] in LDS, then row-vector writes
  __syncthreads();  // done reading As
  uint16_t* T = (uint16_t*)As;
  for (int fi = 0; fi < 4; ++fi)
    for (int r = 0; r < 4; ++r)
      T[(fi * 16 + l16) * 72 + wave * 16 + quad * 4 + r] = f2bf(acc[fi][r]);
  __syncthreads();
  int f = t >> 2, seg = t & 3;
  uint4 v0 = *(const uint4*)&T[f * 72 + seg * 16];
  uint4 v1 = *(const uint4*)&T[f * 72 + seg * 16 + 8];
  uint16_t* dp = xwT + ((size_t)b * FF + f) * NN + n0 + seg * 16;
  *(uint4*)dp = v0;
  *(uint4*)(dp + 8) = v1;
}

// ---------------- Y = A @ X, 64-row tiles, 1024 blocks, 1 barrier/K-step ---------
// A fp32 read direct + reg-staged to bf16 LDS. Raw s_barrier (no vmcnt drain) so
// next-tile loads stay in flight across the barrier; 4 blocks/CU, 16 waves/CU.
// EPI=0: write Y bf16 to Yb [b][n][f] AND YbT [b][f][n] (fused transpose).
// EPI=1: out = ka*xw + kb*y1 + kc*Y + bias (fp32)
template <int EPI>
__global__ __launch_bounds__(256, 4) void k_gemm(const float* __restrict__ adj,
                                                 const uint16_t* __restrict__ Bt,
                                                 uint16_t* __restrict__ Yb,
                                                 uint16_t* __restrict__ YbT,
                                                 const uint16_t* __restrict__ xw,
                                                 const uint16_t* __restrict__ y1,
                                                 const float* __restrict__ Kc,
                                                 const float* __restrict__ bias,
                                                 float* __restrict__ out) {
  __shared__ short As[2][64 * 72];  // 2 x 9 KiB bf16, pad stride 72
  __shared__ short Bs[2][64 * 72];  // 2 x 9 KiB
  int bid = blockIdx.x;
  int b = bid & 31;   // batch-minor: batch b pinned to XCD b%8 -> B-tile L2 reuse
  int rt = bid >> 5;  // 32 row-tiles of 64
  int row0 = rt << 6;
  int t = threadIdx.x;
  int lane = t & 63, wave = t >> 6;
  int l16 = lane & 15, quad = lane >> 4;
  int krot = ((b * 11) + rt * 7) & 31;  // K rotation spreads DRAM pages
  const float* Ab = adj + (size_t)b * NN * NN + (size_t)row0 * NN;
  const uint16_t* Btb = Bt + (size_t)b * FF * NN;

  // staging decomposition: A 16KB fp32 = 1024 float4 (4/thread); B 8KB = 512 uint4
  int ra[4], ca[4];
  for (int i = 0; i < 4; ++i) {
    int chunk = t + i * 256;
    ra[i] = chunk >> 4;
    ca[i] = (chunk & 15) * 4;
  }
  int fb[2], kb8[2];
  for (int j = 0; j < 2; ++j) {
    int chunk = t + j * 256;
    fb[j] = chunk >> 3;
    kb8[j] = (chunk & 7) * 8;
  }

  float4 areg[4];
  uint4 breg[2];
  {
    int kn = krot * 64;
    for (int i = 0; i < 4; ++i)
      areg[i] = *(const float4*)(Ab + (size_t)ra[i] * NN + kn + ca[i]);
    for (int j = 0; j < 2; ++j)
      breg[j] = *(const uint4*)(Btb + (size_t)fb[j] * NN + kn + kb8[j]);
  }

  f32x4 acc[4] = {};
  for (int it = 0; it < 32; ++it) {
    asm volatile("s_waitcnt vmcnt(0)" ::: "memory");  // tile 'it' regs landed
    int p = it & 1;
    for (int i = 0; i < 4; ++i) {
      float4 v = areg[i];
      uint32_t p0 = f2bf(v.x) | ((uint32_t)f2bf(v.y) << 16);
      uint32_t p1 = f2bf(v.z) | ((uint32_t)f2bf(v.w) << 16);
      uint2 pv = {p0, p1};
      *(uint2*)&As[p][ra[i] * 72 + ca[i]] = pv;
    }
    for (int j = 0; j < 2; ++j)
      *(uint4*)&Bs[p][fb[j] * 72 + kb8[j]] = breg[j];
    if (it + 1 < 32) {  // issue next tile; stays in flight across the barrier
      int kn = ((krot + it + 1) & 31) * 64;
      for (int i = 0; i < 4; ++i)
        areg[i] = *(const float4*)(Ab + (size_t)ra[i] * NN + kn + ca[i]);
      for (int j = 0; j < 2; ++j)
        breg[j] = *(const uint4*)(Btb + (size_t)fb[j] * NN + kn + kb8[j]);
    }
    asm volatile("s_waitcnt lgkmcnt(0)" ::: "memory");  // my ds_writes done
    __builtin_amdgcn_s_barrier();                       // raw: no vmcnt drain
    for (int ks = 0; ks < 2; ++ks) {
      bf16x8 a = *(const bf16x8*)&As[p][(wave * 16 + l16) * 72 + ks * 32 + quad * 8];
      for (int fi = 0; fi < 4; ++fi) {
        bf16x8 bq = *(const bf16x8*)&Bs[p][(fi * 16 + l16) * 72 + ks * 32 + quad * 8];
        acc[fi] = __builtin_amdgcn_mfma_f32_16x16x32_bf16(a, bq, acc[fi], 0, 0, 0);
      }
    }
    // safe with ONE barrier: buf p is next overwritten at iter it+2, which is
    // beyond barrier(it+1); frag reads here are consumed by MFMAs (lgkm-waited)
    // before this wave reaches barrier(it+1).
  }

  if (EPI == 0) {
    for (int fi = 0; fi < 4; ++fi)
      for (int r = 0; r < 4; ++r) {
        int n = row0 + wave * 16 + quad * 4 + r;
        int f = fi * 16 + l16;
        Yb[((size_t)b * NN + n) * FF + f] = f2bf(acc[fi][r]);
      }
    // fused transpose -> YbT [b][f][n]
    __syncthreads();
    uint16_t* T = (uint16_t*)&As[0][0];
    for (int fi = 0; fi < 4; ++fi)
      for (int r = 0; r < 4; ++r)
        T[(fi * 16 + l16) * 72 + wave * 16 + quad * 4 + r] = f2bf(acc[fi][r]);
    __syncthreads();
    int f = t >> 2, seg = t & 3;
    uint4 v0 = *(const uint4*)&T[f * 72 + seg * 16];
    uint4 v1 = *(const uint4*)&T[f * 72 + seg * 16 + 8];
    uint16_t* dp = YbT + ((size_t)b * FF + f) * NN + row0 + seg * 16;
    *(uint4*)dp = v0;
    *(uint4*)(dp + 8) = v1;
  } else {
    float ka = Kc[0] - Kc[2], kb = Kc[1], kc = 2.0f * Kc[2];
    for (int fi = 0; fi < 4; ++fi) {
      int f = fi * 16 + l16;
      float bv = bias[f];
      for (int r = 0; r < 4; ++r) {
        int n = row0 + wave * 16 + quad * 4 + r;
        size_t idx = ((size_t)b * NN + n) * FF + f;
        out[idx] = ka * bf2f(xw[idx]) + kb * bf2f(y1[idx]) + kc * acc[fi][r] + bv;
      }
    }
  }
}

extern "C" void kernel_launch(void* const* d_in, const int* in_sizes, int n_in,
                              void* d_out, int out_size, void* d_ws, size_t ws_size,
                              hipStream_t stream) {
  const float* x    = (const float*)d_in[0];
  const float* adj  = (const float*)d_in[1];
  const float* W    = (const float*)d_in[2];
  const float* K    = (const float*)d_in[3];
  const float* bias = (const float*)d_in[4];
  float* out = (float*)d_out;

  uint8_t* ws = (uint8_t*)d_ws;
  const size_t SZ = (size_t)NB * NN * FF * sizeof(uint16_t);  // 8 MiB per buffer
  uint16_t* xw_n = (uint16_t*)(ws);
  uint16_t* xwT  = (uint16_t*)(ws + SZ);
  uint16_t* y1_n = (uint16_t*)(ws + 2 * SZ);
  uint16_t* y1T  = (uint16_t*)(ws + 3 * SZ);
  uint16_t* Wt   = (uint16_t*)(ws + 4 * SZ);

  k_prep<<<dim3(1), dim3(256), 0, stream>>>(W, Wt);
  k_xw<<<dim3(1024), dim3(256), 0, stream>>>(x, Wt, xw_n, xwT);
  k_gemm<0><<<dim3(1024), dim3(256), 0, stream>>>(adj, xwT, y1_n, y1T, nullptr,
                                                  nullptr, nullptr, nullptr, nullptr);
  k_gemm<1><<<dim3(1024), dim3(256), 0, stream>>>(adj, y1T, nullptr, nullptr, xw_n,
                                                  y1_n, K, bias, out);
}